// Round 10
// baseline (361.891 us; speedup 1.0000x reference)
//
#include <hip/hip_runtime.h>
#include <hip/hip_bf16.h>

// Problem constants: B=4, C=256, H=W=64, N=4096, Cq=32
#define NB 4
#define NC 256
#define NQ 32
#define NN 4096
#define LOG2E 1.4426950408889634f
#define SHIFT 44.0f   // fixed softmax shift: E>=0 (post-ReLU)

typedef __attribute__((ext_vector_type(4))) float f32x4;
typedef __attribute__((ext_vector_type(8))) short s16x8;

#define MFMA16(a, b, c) __builtin_amdgcn_mfma_f32_16x16x32_bf16((a), (b), (c), 0, 0, 0)

// native 2^x (v_exp_f32); avoids math.h __exp2f macro clash
__device__ __forceinline__ float fexp2(float x) {
    float r;
    asm("v_exp_f32 %0, %1" : "=v"(r) : "v"(x));
    return r;
}

// ---------------- K1: fused QKV 1x1-conv projection (fp32 VALU) ----------------
// grid (N/32, B), block 512, LDS x tile [256c][32n] = 32 KB.
__global__ __launch_bounds__(512, 3) void k_proj(
    const float* __restrict__ x,
    const float* __restrict__ Wq, const float* __restrict__ bq,
    const float* __restrict__ Wk, const float* __restrict__ bk,
    const float* __restrict__ Wv, const float* __restrict__ bv,
    __hip_bfloat16* __restrict__ qh, __hip_bfloat16* __restrict__ ql,
    __hip_bfloat16* __restrict__ kh, __hip_bfloat16* __restrict__ kl,
    __hip_bfloat16* __restrict__ vo)
{
    __shared__ __align__(16) float xs[NC * 32];
    const int b  = blockIdx.y;
    const int n0 = blockIdx.x * 32;
    const int t  = threadIdx.x;

    {
        const float* xb = x + (size_t)b * NC * NN + n0;
        #pragma unroll
        for (int it = 0; it < 4; ++it) {
            int i4 = t + it * 512;            // 0..2047
            int c  = i4 >> 3;
            int nq = (i4 & 7) << 2;
            float4 v4 = *(const float4*)(xb + (size_t)c * NN + nq);
            *(float4*)&xs[c * 32 + nq] = v4;
        }
    }
    __syncthreads();

    const int g  = t >> 3;            // 0..63
    const int n4 = (t & 7) << 2;      // 0,4,...,28

    const float* Wr[5];
    float a[5][4];
    #pragma unroll
    for (int j = 0; j < 5; ++j) {
        int o = g + 64 * j;
        const float* Wrow; float bias;
        if (o < 32)      { Wrow = Wq + o * NC;        bias = bq[o]; }
        else if (o < 64) { Wrow = Wk + (o - 32) * NC; bias = bk[o - 32]; }
        else             { Wrow = Wv + (o - 64) * NC; bias = bv[o - 64]; }
        Wr[j] = Wrow;
        a[j][0] = a[j][1] = a[j][2] = a[j][3] = bias;
    }

    #pragma unroll 2
    for (int c0 = 0; c0 < NC; c0 += 4) {
        float4 xv[4];
        #pragma unroll
        for (int i = 0; i < 4; ++i) xv[i] = *(const float4*)&xs[(c0 + i) * 32 + n4];
        #pragma unroll
        for (int j = 0; j < 5; ++j) {
            float4 w = *(const float4*)(Wr[j] + c0);
            a[j][0] += w.x * xv[0].x + w.y * xv[1].x + w.z * xv[2].x + w.w * xv[3].x;
            a[j][1] += w.x * xv[0].y + w.y * xv[1].y + w.z * xv[2].y + w.w * xv[3].y;
            a[j][2] += w.x * xv[0].z + w.y * xv[1].z + w.z * xv[2].z + w.w * xv[3].z;
            a[j][3] += w.x * xv[0].w + w.y * xv[1].w + w.z * xv[2].w + w.w * xv[3].w;
        }
    }

    #pragma unroll
    for (int j = 0; j < 5; ++j) {
        int o = g + 64 * j;
        float a0 = fmaxf(a[j][0], 0.f), a1 = fmaxf(a[j][1], 0.f);
        float a2 = fmaxf(a[j][2], 0.f), a3 = fmaxf(a[j][3], 0.f);
        int nn = n0 + n4;
        if (o < 64) {
            __hip_bfloat16 *dh, *dl; int c; float sc;
            if (o < 32) { dh = qh; dl = ql; c = o;      sc = LOG2E; }  // exp2 domain
            else        { dh = kh; dl = kl; c = o - 32; sc = 1.0f;  }
            float vals[4] = {a0 * sc, a1 * sc, a2 * sc, a3 * sc};
            #pragma unroll
            for (int i = 0; i < 4; ++i) {
                float vv = vals[i];
                __hip_bfloat16 h = __float2bfloat16(vv);
                float lo = vv - __bfloat162float(h);
                size_t base = ((size_t)b * NN + nn + i) * NQ + c;
                dh[base] = h;
                dl[base] = __float2bfloat16(lo);
            }
        } else {
            union { __hip_bfloat16 h[4]; unsigned long long u; } pk;
            pk.h[0] = __float2bfloat16(a0); pk.h[1] = __float2bfloat16(a1);
            pk.h[2] = __float2bfloat16(a2); pk.h[3] = __float2bfloat16(a3);
            *(unsigned long long*)(vo + ((size_t)b * NC + (o - 64)) * NN + nn) = pk.u;
        }
    }
}

// ---------------- K2: fused attention — BARRIER-FREE main loop ----------------
// grid 512 (XCD-swizzled), block 256 = 4 waves. Block = 32n x 256c; wave = 64c x 32n.
// Pass 1 (4 waves: rs=wv&1 row-half, mh=wv>>1 m-half): fixed-shift row sums -> finI.
// Pass 2: each wave fully independent, sweeps all m in 32-m steps:
//   QK 16x16x32 with PERMUTED k-rows (tile0 rows (r>>2)*8+(r&3), tile1 +4) so the
//   two tile outputs per lane are 8 consecutive m at n=lane&15 == PV B-frag layout.
//   exp2 -> att NT store (fp32 from regs) -> pack bf16 -> 8 PV MFMAs vs reg v-frags.
//   k and v prefetched one step ahead into registers. NO LDS, NO barriers.
__global__ __launch_bounds__(256, 2) void k_fused(
    const __hip_bfloat16* __restrict__ qh, const __hip_bfloat16* __restrict__ ql,
    const __hip_bfloat16* __restrict__ kh, const __hip_bfloat16* __restrict__ kl,
    const __hip_bfloat16* __restrict__ v,
    const float* __restrict__ x, const float* __restrict__ gamma,
    float* __restrict__ out, float* __restrict__ att)
{
    __shared__ float redS[4][16];
    __shared__ float finI[32];

    // XCD chunked swizzle: 64 consecutive flat blocks per XCD (half a batch)
    const int bid  = blockIdx.x;
    const int flat = (bid & 7) * 64 + (bid >> 3);
    const int b    = flat >> 7;
    const int n0   = (flat & 127) * 32;

    const int t = threadIdx.x, wv = t >> 6, lane = t & 63;
    const int r = lane & 15, hi = lane >> 4, kc = hi * 8, h8 = hi * 8;

    const __hip_bfloat16* khb = kh + (size_t)b * NN * NQ;
    const __hip_bfloat16* klb = kl + (size_t)b * NN * NQ;
    const __hip_bfloat16* vb  = v  + (size_t)b * NC * NN;
    const __hip_bfloat16* qhb = qh + ((size_t)b * NN + n0) * NQ;
    const __hip_bfloat16* qlb = ql + ((size_t)b * NN + n0) * NQ;

    // ---- pass 1: fixed-shift row sums (rs = wv&1 row-half, mh = wv>>1 m-half) ----
    {
        const int rs = wv & 1, mh = wv >> 1;
        const s16x8 aqh = *(const s16x8*)(qhb + (size_t)(rs * 16 + r) * NQ + kc);
        const s16x8 aql = *(const s16x8*)(qlb + (size_t)(rs * 16 + r) * NQ + kc);
        const int mb = mh * 2048;
        float S = 0.f;
        s16x8 c0h = *(const s16x8*)(khb + (size_t)(mb + r) * NQ + kc);
        s16x8 c0l = *(const s16x8*)(klb + (size_t)(mb + r) * NQ + kc);
        s16x8 c1h = *(const s16x8*)(khb + (size_t)(mb + 16 + r) * NQ + kc);
        s16x8 c1l = *(const s16x8*)(klb + (size_t)(mb + 16 + r) * NQ + kc);
        #pragma unroll 1
        for (int it = 0; it < 64; ++it) {
            s16x8 u0h = c0h, u0l = c0l, u1h = c1h, u1l = c1l;
            if (it < 63) {
                int m = mb + (it + 1) * 32;
                c0h = *(const s16x8*)(khb + (size_t)(m + r) * NQ + kc);
                c0l = *(const s16x8*)(klb + (size_t)(m + r) * NQ + kc);
                c1h = *(const s16x8*)(khb + (size_t)(m + 16 + r) * NQ + kc);
                c1l = *(const s16x8*)(klb + (size_t)(m + 16 + r) * NQ + kc);
            }
            f32x4 e0 = {0.f, 0.f, 0.f, 0.f}, e1 = {0.f, 0.f, 0.f, 0.f};
            e0 = MFMA16(u0h, aqh, e0); e0 = MFMA16(u0l, aqh, e0); e0 = MFMA16(u0h, aql, e0);
            e1 = MFMA16(u1h, aqh, e1); e1 = MFMA16(u1l, aqh, e1); e1 = MFMA16(u1h, aql, e1);
            S += fexp2(e0[0] - SHIFT) + fexp2(e0[1] - SHIFT) +
                 fexp2(e0[2] - SHIFT) + fexp2(e0[3] - SHIFT) +
                 fexp2(e1[0] - SHIFT) + fexp2(e1[1] - SHIFT) +
                 fexp2(e1[2] - SHIFT) + fexp2(e1[3] - SHIFT);
        }
        S += __shfl_xor(S, 16);
        S += __shfl_xor(S, 32);
        if (lane < 16) redS[wv][r] = S;
    }
    __syncthreads();
    if (t < 32) {
        const int rs = t >> 4, tl = t & 15;
        finI[t] = 1.0f / (redS[rs][tl] + redS[2 + rs][tl]);
    }
    __syncthreads();

    // ---- pass 2: barrier-free fused sweep ----
    const int cw = wv * 64;
    const s16x8 aqh0 = *(const s16x8*)(qhb + (size_t)(r) * NQ + kc);
    const s16x8 aql0 = *(const s16x8*)(qlb + (size_t)(r) * NQ + kc);
    const s16x8 aqh1 = *(const s16x8*)(qhb + (size_t)(16 + r) * NQ + kc);
    const s16x8 aql1 = *(const s16x8*)(qlb + (size_t)(16 + r) * NQ + kc);
    const float fI0 = finI[r], fI1 = finI[16 + r];

    float* arow0 = att + ((size_t)b * NN + n0 + r) * NN;
    float* arow1 = arow0 + (size_t)16 * NN;

    // permuted k-row pointers: tile0 row = (r>>2)*8 + (r&3), tile1 = +4
    const int p0r = ((r >> 2) << 3) | (r & 3);
    const __hip_bfloat16* kh0 = khb + (size_t)p0r * NQ + kc;
    const __hip_bfloat16* kl0 = klb + (size_t)p0r * NQ + kc;
    const __hip_bfloat16* kh1 = khb + (size_t)(p0r + 4) * NQ + kc;
    const __hip_bfloat16* kl1 = klb + (size_t)(p0r + 4) * NQ + kc;
    const __hip_bfloat16* vr0 = vb + (size_t)(cw + r) * NN + kc;
    const __hip_bfloat16* vr1 = vb + (size_t)(cw + 16 + r) * NN + kc;
    const __hip_bfloat16* vr2 = vb + (size_t)(cw + 32 + r) * NN + kc;
    const __hip_bfloat16* vr3 = vb + (size_t)(cw + 48 + r) * NN + kc;

    f32x4 acc[4][2] = {};
    s16x8 kA[4], kB[4], vA[4], vB[4];

    // prologue: step-0 fragments
    kA[0] = *(const s16x8*)(kh0); kA[1] = *(const s16x8*)(kl0);
    kA[2] = *(const s16x8*)(kh1); kA[3] = *(const s16x8*)(kl1);
    vA[0] = *(const s16x8*)(vr0); vA[1] = *(const s16x8*)(vr1);
    vA[2] = *(const s16x8*)(vr2); vA[3] = *(const s16x8*)(vr3);

    auto sub = [&](int s, s16x8 (&kC)[4], s16x8 (&kN)[4],
                   s16x8 (&vC)[4], s16x8 (&vN)[4]) {
        const int m0 = s * 32;
        if (s < 127) {
            const size_t mo = (size_t)(m0 + 32) * NQ;
            kN[0] = *(const s16x8*)(kh0 + mo); kN[1] = *(const s16x8*)(kl0 + mo);
            kN[2] = *(const s16x8*)(kh1 + mo); kN[3] = *(const s16x8*)(kl1 + mo);
            vN[0] = *(const s16x8*)(vr0 + m0 + 32); vN[1] = *(const s16x8*)(vr1 + m0 + 32);
            vN[2] = *(const s16x8*)(vr2 + m0 + 32); vN[3] = *(const s16x8*)(vr3 + m0 + 32);
        }
        // QK: 2 n-subtiles x 2 permuted m-tiles; lane(r,hi) j-th value of tile T
        // = E[m0 + hi*8 + 4T + j][n = nsub*16 + r]
        f32x4 e00 = {0.f,0.f,0.f,0.f}, e01 = {0.f,0.f,0.f,0.f};
        f32x4 e10 = {0.f,0.f,0.f,0.f}, e11 = {0.f,0.f,0.f,0.f};
        e00 = MFMA16(kC[0], aqh0, e00); e00 = MFMA16(kC[1], aqh0, e00); e00 = MFMA16(kC[0], aql0, e00);
        e01 = MFMA16(kC[2], aqh0, e01); e01 = MFMA16(kC[3], aqh0, e01); e01 = MFMA16(kC[2], aql0, e01);
        e10 = MFMA16(kC[0], aqh1, e10); e10 = MFMA16(kC[1], aqh1, e10); e10 = MFMA16(kC[0], aql1, e10);
        e11 = MFMA16(kC[2], aqh1, e11); e11 = MFMA16(kC[3], aqh1, e11); e11 = MFMA16(kC[2], aql1, e11);

        f32x4 p00, p01, p10, p11;
        #pragma unroll
        for (int j = 0; j < 4; ++j) {
            p00[j] = fexp2(e00[j] - SHIFT) * fI0;
            p01[j] = fexp2(e01[j] - SHIFT) * fI0;
            p10[j] = fexp2(e10[j] - SHIFT) * fI1;
            p11[j] = fexp2(e11[j] - SHIFT) * fI1;
        }
        // att: fp32 NT stores straight from regs (row n, 8 consecutive m per lane)
        __builtin_nontemporal_store(p00, (f32x4*)(arow0 + m0 + h8));
        __builtin_nontemporal_store(p01, (f32x4*)(arow0 + m0 + h8 + 4));
        __builtin_nontemporal_store(p10, (f32x4*)(arow1 + m0 + h8));
        __builtin_nontemporal_store(p11, (f32x4*)(arow1 + m0 + h8 + 4));
        // pack PV B-frags: lane(r,hi) holds P[n=r][m0 + hi*8 + 0..7]
        union { short s[8]; s16x8 v; } u0, u1;
        #pragma unroll
        for (int j = 0; j < 4; ++j) {
            u0.s[j]     = (short)__bfloat16_as_ushort(__float2bfloat16(p00[j]));
            u0.s[4 + j] = (short)__bfloat16_as_ushort(__float2bfloat16(p01[j]));
            u1.s[j]     = (short)__bfloat16_as_ushort(__float2bfloat16(p10[j]));
            u1.s[4 + j] = (short)__bfloat16_as_ushort(__float2bfloat16(p11[j]));
        }
        // PV: 4 c-subtiles x 2 n-subtiles
        acc[0][0] = MFMA16(vC[0], u0.v, acc[0][0]);
        acc[1][0] = MFMA16(vC[1], u0.v, acc[1][0]);
        acc[2][0] = MFMA16(vC[2], u0.v, acc[2][0]);
        acc[3][0] = MFMA16(vC[3], u0.v, acc[3][0]);
        acc[0][1] = MFMA16(vC[0], u1.v, acc[0][1]);
        acc[1][1] = MFMA16(vC[1], u1.v, acc[1][1]);
        acc[2][1] = MFMA16(vC[2], u1.v, acc[2][1]);
        acc[3][1] = MFMA16(vC[3], u1.v, acc[3][1]);
    };

    #pragma unroll 1
    for (int it = 0; it < 64; ++it) {
        sub(2 * it,     kA, kB, vA, vB);
        sub(2 * it + 1, kB, kA, vB, vA);
    }

    // epilogue: out = gamma*acc + x  (c = cw + cc*16 + hi*4 + j, n = n0 + ns*16 + r)
    const float gm = gamma[0];
    #pragma unroll
    for (int cc = 0; cc < 4; ++cc) {
        #pragma unroll
        for (int ns = 0; ns < 2; ++ns) {
            #pragma unroll
            for (int j = 0; j < 4; ++j) {
                int c = cw + cc * 16 + hi * 4 + j;
                size_t idx = ((size_t)b * NC + c) * NN + n0 + ns * 16 + r;
                out[idx] = gm * acc[cc][ns][j] + x[idx];
            }
        }
    }
}

extern "C" void kernel_launch(void* const* d_in, const int* in_sizes, int n_in,
                              void* d_out, int out_size, void* d_ws, size_t ws_size,
                              hipStream_t stream) {
    const float* x     = (const float*)d_in[0];
    const float* Wq    = (const float*)d_in[1];
    const float* bq    = (const float*)d_in[2];
    const float* Wk    = (const float*)d_in[3];
    const float* bk    = (const float*)d_in[4];
    const float* Wv    = (const float*)d_in[5];
    const float* bv    = (const float*)d_in[6];
    const float* gamma = (const float*)d_in[7];

    float* out = (float*)d_out;
    float* att = out + (size_t)NB * NC * NN;   // attention output region (268 MB)

    // workspace: qh | ql | kh | kl (each B*N*32 bf16 = 1 MB) | v bf16 (8 MB)
    const size_t qk_elems = (size_t)NB * NN * NQ;
    __hip_bfloat16* qh = (__hip_bfloat16*)d_ws;
    __hip_bfloat16* ql = qh + qk_elems;
    __hip_bfloat16* kh = ql + qk_elems;
    __hip_bfloat16* kl = kh + qk_elems;
    __hip_bfloat16* vo = kl + qk_elems;

    k_proj <<<dim3(NN / 32, NB), 512, 0, stream>>>(x, Wq, bq, Wk, bk, Wv, bv,
                                                   qh, ql, kh, kl, vo);
    k_fused<<<dim3(512), 256, 0, stream>>>(qh, ql, kh, kl, vo,
                                           x, gamma, out, att);
}

// Round 11
// 344.521 us; speedup vs baseline: 1.0504x; 1.0504x over previous
//
#include <hip/hip_runtime.h>
#include <hip/hip_bf16.h>

// Problem constants: B=4, C=256, H=W=64, N=4096, Cq=32
#define NB 4
#define NC 256
#define NQ 32
#define NN 4096
#define LOG2E 1.4426950408889634f
#define SHIFT 44.0f   // fixed softmax shift: E>=0 (post-ReLU)

typedef __attribute__((ext_vector_type(4))) float f32x4;
typedef __attribute__((ext_vector_type(8))) short s16x8;

#define MFMA16(a, b, c) __builtin_amdgcn_mfma_f32_16x16x32_bf16((a), (b), (c), 0, 0, 0)

// native 2^x (v_exp_f32); avoids math.h __exp2f macro clash
__device__ __forceinline__ float fexp2(float x) {
    float r;
    asm("v_exp_f32 %0, %1" : "=v"(r) : "v"(x));
    return r;
}

__device__ __forceinline__ unsigned long long packbf4(f32x4 p) {
    union { __hip_bfloat16 h[4]; unsigned long long u; } pk;
    #pragma unroll
    for (int j = 0; j < 4; ++j) pk.h[j] = __float2bfloat16(p[j]);
    return pk.u;
}

// ---------------- K1: fused QKV 1x1-conv projection (fp32 VALU) ----------------
// grid (N/32, B), block 512, LDS x tile [256c][32n] = 32 KB.
__global__ __launch_bounds__(512, 3) void k_proj(
    const float* __restrict__ x,
    const float* __restrict__ Wq, const float* __restrict__ bq,
    const float* __restrict__ Wk, const float* __restrict__ bk,
    const float* __restrict__ Wv, const float* __restrict__ bv,
    __hip_bfloat16* __restrict__ qh, __hip_bfloat16* __restrict__ ql,
    __hip_bfloat16* __restrict__ kh, __hip_bfloat16* __restrict__ kl,
    __hip_bfloat16* __restrict__ vo)
{
    __shared__ __align__(16) float xs[NC * 32];
    const int b  = blockIdx.y;
    const int n0 = blockIdx.x * 32;
    const int t  = threadIdx.x;

    {
        const float* xb = x + (size_t)b * NC * NN + n0;
        #pragma unroll
        for (int it = 0; it < 4; ++it) {
            int i4 = t + it * 512;            // 0..2047
            int c  = i4 >> 3;
            int nq = (i4 & 7) << 2;
            float4 v4 = *(const float4*)(xb + (size_t)c * NN + nq);
            *(float4*)&xs[c * 32 + nq] = v4;
        }
    }
    __syncthreads();

    const int g  = t >> 3;            // 0..63
    const int n4 = (t & 7) << 2;      // 0,4,...,28

    const float* Wr[5];
    float a[5][4];
    #pragma unroll
    for (int j = 0; j < 5; ++j) {
        int o = g + 64 * j;
        const float* Wrow; float bias;
        if (o < 32)      { Wrow = Wq + o * NC;        bias = bq[o]; }
        else if (o < 64) { Wrow = Wk + (o - 32) * NC; bias = bk[o - 32]; }
        else             { Wrow = Wv + (o - 64) * NC; bias = bv[o - 64]; }
        Wr[j] = Wrow;
        a[j][0] = a[j][1] = a[j][2] = a[j][3] = bias;
    }

    #pragma unroll 2
    for (int c0 = 0; c0 < NC; c0 += 4) {
        float4 xv[4];
        #pragma unroll
        for (int i = 0; i < 4; ++i) xv[i] = *(const float4*)&xs[(c0 + i) * 32 + n4];
        #pragma unroll
        for (int j = 0; j < 5; ++j) {
            float4 w = *(const float4*)(Wr[j] + c0);
            a[j][0] += w.x * xv[0].x + w.y * xv[1].x + w.z * xv[2].x + w.w * xv[3].x;
            a[j][1] += w.x * xv[0].y + w.y * xv[1].y + w.z * xv[2].y + w.w * xv[3].y;
            a[j][2] += w.x * xv[0].z + w.y * xv[1].z + w.z * xv[2].z + w.w * xv[3].z;
            a[j][3] += w.x * xv[0].w + w.y * xv[1].w + w.z * xv[2].w + w.w * xv[3].w;
        }
    }

    #pragma unroll
    for (int j = 0; j < 5; ++j) {
        int o = g + 64 * j;
        float a0 = fmaxf(a[j][0], 0.f), a1 = fmaxf(a[j][1], 0.f);
        float a2 = fmaxf(a[j][2], 0.f), a3 = fmaxf(a[j][3], 0.f);
        int nn = n0 + n4;
        if (o < 64) {
            __hip_bfloat16 *dh, *dl; int c; float sc;
            if (o < 32) { dh = qh; dl = ql; c = o;      sc = LOG2E; }  // exp2 domain
            else        { dh = kh; dl = kl; c = o - 32; sc = 1.0f;  }
            float vals[4] = {a0 * sc, a1 * sc, a2 * sc, a3 * sc};
            #pragma unroll
            for (int i = 0; i < 4; ++i) {
                float vv = vals[i];
                __hip_bfloat16 h = __float2bfloat16(vv);
                float lo = vv - __bfloat162float(h);
                size_t base = ((size_t)b * NN + nn + i) * NQ + c;
                dh[base] = h;
                dl[base] = __float2bfloat16(lo);
            }
        } else {
            union { __hip_bfloat16 h[4]; unsigned long long u; } pk;
            pk.h[0] = __float2bfloat16(a0); pk.h[1] = __float2bfloat16(a1);
            pk.h[2] = __float2bfloat16(a2); pk.h[3] = __float2bfloat16(a3);
            *(unsigned long long*)(vo + ((size_t)b * NC + (o - 64)) * NN + nn) = pk.u;
        }
    }
}

// ---------------- K2: fused attention — barrier-free, clean-sector writes ----------------
// grid 512 (XCD-swizzled), block 256 = 4 waves. Block = 32n x 256c; wave = 64c x 32n.
// Per 32-m step: QK as two IDENTITY 16x16 tiles per n-sub (m0..15, m0+16..31) so
// lane (r,hi) holds 4 consecutive m at m0+hi*4 / m0+16+hi*4 -> NT f32x4 stores
// cover full 64-B sectors per row (no write amplification). PV B-frag (8 consec m
// per lane) rebuilt via per-wave PRIVATE LDS round-trip (2 KB/wave, 16B-granule
// XOR swizzle, intra-wave ordering only — NO barriers in the loop).
__global__ __launch_bounds__(256, 2) void k_fused(
    const __hip_bfloat16* __restrict__ qh, const __hip_bfloat16* __restrict__ ql,
    const __hip_bfloat16* __restrict__ kh, const __hip_bfloat16* __restrict__ kl,
    const __hip_bfloat16* __restrict__ v,
    const float* __restrict__ x, const float* __restrict__ gamma,
    float* __restrict__ out, float* __restrict__ att)
{
    __shared__ __align__(16) char plds[8192];   // 4 waves x 2 ns x [16 r][32 m] bf16
    __shared__ float redS[4][16];
    __shared__ float finI[32];

    // XCD chunked swizzle: 64 consecutive flat blocks per XCD (half a batch)
    const int bid  = blockIdx.x;
    const int flat = (bid & 7) * 64 + (bid >> 3);
    const int b    = flat >> 7;
    const int n0   = (flat & 127) * 32;

    const int t = threadIdx.x, wv = t >> 6, lane = t & 63;
    const int r = lane & 15, hi = lane >> 4, kc = hi * 8;

    const __hip_bfloat16* khb = kh + (size_t)b * NN * NQ;
    const __hip_bfloat16* klb = kl + (size_t)b * NN * NQ;
    const __hip_bfloat16* vb  = v  + (size_t)b * NC * NN;
    const __hip_bfloat16* qhb = qh + ((size_t)b * NN + n0) * NQ;
    const __hip_bfloat16* qlb = ql + ((size_t)b * NN + n0) * NQ;

    // ---- pass 1: fixed-shift row sums (rs = wv&1 row-half, mh = wv>>1 m-half) ----
    {
        const int rs = wv & 1, mh = wv >> 1;
        const s16x8 aqh = *(const s16x8*)(qhb + (size_t)(rs * 16 + r) * NQ + kc);
        const s16x8 aql = *(const s16x8*)(qlb + (size_t)(rs * 16 + r) * NQ + kc);
        const int mb = mh * 2048;
        float S = 0.f;
        s16x8 c0h = *(const s16x8*)(khb + (size_t)(mb + r) * NQ + kc);
        s16x8 c0l = *(const s16x8*)(klb + (size_t)(mb + r) * NQ + kc);
        s16x8 c1h = *(const s16x8*)(khb + (size_t)(mb + 16 + r) * NQ + kc);
        s16x8 c1l = *(const s16x8*)(klb + (size_t)(mb + 16 + r) * NQ + kc);
        #pragma unroll 1
        for (int it = 0; it < 64; ++it) {
            s16x8 u0h = c0h, u0l = c0l, u1h = c1h, u1l = c1l;
            if (it < 63) {
                int m = mb + (it + 1) * 32;
                c0h = *(const s16x8*)(khb + (size_t)(m + r) * NQ + kc);
                c0l = *(const s16x8*)(klb + (size_t)(m + r) * NQ + kc);
                c1h = *(const s16x8*)(khb + (size_t)(m + 16 + r) * NQ + kc);
                c1l = *(const s16x8*)(klb + (size_t)(m + 16 + r) * NQ + kc);
            }
            f32x4 e0 = {0.f, 0.f, 0.f, 0.f}, e1 = {0.f, 0.f, 0.f, 0.f};
            e0 = MFMA16(u0h, aqh, e0); e0 = MFMA16(u0l, aqh, e0); e0 = MFMA16(u0h, aql, e0);
            e1 = MFMA16(u1h, aqh, e1); e1 = MFMA16(u1l, aqh, e1); e1 = MFMA16(u1h, aql, e1);
            S += fexp2(e0[0] - SHIFT) + fexp2(e0[1] - SHIFT) +
                 fexp2(e0[2] - SHIFT) + fexp2(e0[3] - SHIFT) +
                 fexp2(e1[0] - SHIFT) + fexp2(e1[1] - SHIFT) +
                 fexp2(e1[2] - SHIFT) + fexp2(e1[3] - SHIFT);
        }
        S += __shfl_xor(S, 16);
        S += __shfl_xor(S, 32);
        if (lane < 16) redS[wv][r] = S;
    }
    __syncthreads();
    if (t < 32) {
        const int rs = t >> 4, tl = t & 15;
        finI[t] = 1.0f / (redS[rs][tl] + redS[2 + rs][tl]);
    }
    __syncthreads();

    // ---- pass 2: barrier-free fused sweep ----
    const int cw = wv * 64;
    const s16x8 aqh0 = *(const s16x8*)(qhb + (size_t)(r) * NQ + kc);
    const s16x8 aql0 = *(const s16x8*)(qlb + (size_t)(r) * NQ + kc);
    const s16x8 aqh1 = *(const s16x8*)(qhb + (size_t)(16 + r) * NQ + kc);
    const s16x8 aql1 = *(const s16x8*)(qlb + (size_t)(16 + r) * NQ + kc);
    const float fI0 = finI[r], fI1 = finI[16 + r];

    float* arow0 = att + ((size_t)b * NN + n0 + r) * NN;
    float* arow1 = arow0 + (size_t)16 * NN;

    // k row pointers (identity tiles: tile0 row = r, tile1 row = 16 + r)
    const __hip_bfloat16* kh0 = khb + (size_t)r * NQ + kc;
    const __hip_bfloat16* kl0 = klb + (size_t)r * NQ + kc;
    const __hip_bfloat16* kh1 = khb + (size_t)(16 + r) * NQ + kc;
    const __hip_bfloat16* kl1 = klb + (size_t)(16 + r) * NQ + kc;
    const __hip_bfloat16* vr0 = vb + (size_t)(cw + r) * NN + kc;
    const __hip_bfloat16* vr1 = vb + (size_t)(cw + 16 + r) * NN + kc;
    const __hip_bfloat16* vr2 = vb + (size_t)(cw + 32 + r) * NN + kc;
    const __hip_bfloat16* vr3 = vb + (size_t)(cw + 48 + r) * NN + kc;

    // per-wave private LDS addresses (16-B granule XOR swizzle, row = 64 B)
    // write1: tile0 u64 at granule (hi>>1), half (hi&1); write2: tile1 at granule 2+(hi>>1)
    // read:   b128 at granule hi  (covers m = hi*8..hi*8+7)
    const int lbase  = wv * 2048 + r * 64;
    const int swz_w0 = lbase + ((((hi >> 1)    ) ^ (r & 3)) << 4) + ((hi & 1) << 3);
    const int swz_w1 = lbase + ((((hi >> 1) + 2) ^ (r & 3)) << 4) + ((hi & 1) << 3);
    const int swz_rd = lbase + ((hi ^ (r & 3)) << 4);

    f32x4 acc[4][2] = {};
    s16x8 kA[4], kB[4], vA[4], vB[4];

    // prologue: step-0 fragments
    kA[0] = *(const s16x8*)(kh0); kA[1] = *(const s16x8*)(kl0);
    kA[2] = *(const s16x8*)(kh1); kA[3] = *(const s16x8*)(kl1);
    vA[0] = *(const s16x8*)(vr0); vA[1] = *(const s16x8*)(vr1);
    vA[2] = *(const s16x8*)(vr2); vA[3] = *(const s16x8*)(vr3);

    auto sub = [&](int s, s16x8 (&kC)[4], s16x8 (&kN)[4],
                   s16x8 (&vC)[4], s16x8 (&vN)[4]) {
        const int m0 = s * 32;
        if (s < 127) {
            const size_t mo = (size_t)(m0 + 32) * NQ;
            kN[0] = *(const s16x8*)(kh0 + mo); kN[1] = *(const s16x8*)(kl0 + mo);
            kN[2] = *(const s16x8*)(kh1 + mo); kN[3] = *(const s16x8*)(kl1 + mo);
            vN[0] = *(const s16x8*)(vr0 + m0 + 32); vN[1] = *(const s16x8*)(vr1 + m0 + 32);
            vN[2] = *(const s16x8*)(vr2 + m0 + 32); vN[3] = *(const s16x8*)(vr3 + m0 + 32);
        }
        // QK identity tiles: lane (r,hi) j-th of tile T = E[m0 + 16T + hi*4 + j][n=ns*16+r]
        f32x4 e00 = {0.f,0.f,0.f,0.f}, e01 = {0.f,0.f,0.f,0.f};
        f32x4 e10 = {0.f,0.f,0.f,0.f}, e11 = {0.f,0.f,0.f,0.f};
        e00 = MFMA16(kC[0], aqh0, e00); e00 = MFMA16(kC[1], aqh0, e00); e00 = MFMA16(kC[0], aql0, e00);
        e01 = MFMA16(kC[2], aqh0, e01); e01 = MFMA16(kC[3], aqh0, e01); e01 = MFMA16(kC[2], aql0, e01);
        e10 = MFMA16(kC[0], aqh1, e10); e10 = MFMA16(kC[1], aqh1, e10); e10 = MFMA16(kC[0], aql1, e10);
        e11 = MFMA16(kC[2], aqh1, e11); e11 = MFMA16(kC[3], aqh1, e11); e11 = MFMA16(kC[2], aql1, e11);

        f32x4 p00, p01, p10, p11;
        #pragma unroll
        for (int j = 0; j < 4; ++j) {
            p00[j] = fexp2(e00[j] - SHIFT) * fI0;
            p01[j] = fexp2(e01[j] - SHIFT) * fI0;
            p10[j] = fexp2(e10[j] - SHIFT) * fI1;
            p11[j] = fexp2(e11[j] - SHIFT) * fI1;
        }
        // att NT stores: per row (r), 4 hi lanes cover 64 B contiguous -> full sectors
        __builtin_nontemporal_store(p00, (f32x4*)(arow0 + m0 + hi * 4));
        __builtin_nontemporal_store(p01, (f32x4*)(arow0 + m0 + 16 + hi * 4));
        __builtin_nontemporal_store(p10, (f32x4*)(arow1 + m0 + hi * 4));
        __builtin_nontemporal_store(p11, (f32x4*)(arow1 + m0 + 16 + hi * 4));

        // PV B-frags via private LDS round-trip (intra-wave, compiler-ordered)
        *(unsigned long long*)(plds + swz_w0)        = packbf4(p00);
        *(unsigned long long*)(plds + swz_w1)        = packbf4(p01);
        *(unsigned long long*)(plds + 1024 + swz_w0) = packbf4(p10);
        *(unsigned long long*)(plds + 1024 + swz_w1) = packbf4(p11);
        s16x8 pf0 = *(const s16x8*)(plds + swz_rd);
        s16x8 pf1 = *(const s16x8*)(plds + 1024 + swz_rd);

        // PV: 4 c-subtiles x 2 n-subtiles
        acc[0][0] = MFMA16(vC[0], pf0, acc[0][0]);
        acc[1][0] = MFMA16(vC[1], pf0, acc[1][0]);
        acc[2][0] = MFMA16(vC[2], pf0, acc[2][0]);
        acc[3][0] = MFMA16(vC[3], pf0, acc[3][0]);
        acc[0][1] = MFMA16(vC[0], pf1, acc[0][1]);
        acc[1][1] = MFMA16(vC[1], pf1, acc[1][1]);
        acc[2][1] = MFMA16(vC[2], pf1, acc[2][1]);
        acc[3][1] = MFMA16(vC[3], pf1, acc[3][1]);
    };

    #pragma unroll 1
    for (int it = 0; it < 64; ++it) {
        sub(2 * it,     kA, kB, vA, vB);
        sub(2 * it + 1, kB, kA, vB, vA);
    }

    // epilogue: out = gamma*acc + x  (c = cw + cc*16 + hi*4 + j, n = n0 + ns*16 + r)
    const float gm = gamma[0];
    #pragma unroll
    for (int cc = 0; cc < 4; ++cc) {
        #pragma unroll
        for (int ns = 0; ns < 2; ++ns) {
            #pragma unroll
            for (int j = 0; j < 4; ++j) {
                int c = cw + cc * 16 + hi * 4 + j;
                size_t idx = ((size_t)b * NC + c) * NN + n0 + ns * 16 + r;
                out[idx] = gm * acc[cc][ns][j] + x[idx];
            }
        }
    }
}

extern "C" void kernel_launch(void* const* d_in, const int* in_sizes, int n_in,
                              void* d_out, int out_size, void* d_ws, size_t ws_size,
                              hipStream_t stream) {
    const float* x     = (const float*)d_in[0];
    const float* Wq    = (const float*)d_in[1];
    const float* bq    = (const float*)d_in[2];
    const float* Wk    = (const float*)d_in[3];
    const float* bk    = (const float*)d_in[4];
    const float* Wv    = (const float*)d_in[5];
    const float* bv    = (const float*)d_in[6];
    const float* gamma = (const float*)d_in[7];

    float* out = (float*)d_out;
    float* att = out + (size_t)NB * NC * NN;   // attention output region (268 MB)

    // workspace: qh | ql | kh | kl (each B*N*32 bf16 = 1 MB) | v bf16 (8 MB)
    const size_t qk_elems = (size_t)NB * NN * NQ;
    __hip_bfloat16* qh = (__hip_bfloat16*)d_ws;
    __hip_bfloat16* ql = qh + qk_elems;
    __hip_bfloat16* kh = ql + qk_elems;
    __hip_bfloat16* kl = kh + qk_elems;
    __hip_bfloat16* vo = kl + qk_elems;

    k_proj <<<dim3(NN / 32, NB), 512, 0, stream>>>(x, Wq, bq, Wk, bk, Wv, bv,
                                                   qh, ql, kh, kl, vo);
    k_fused<<<dim3(512), 256, 0, stream>>>(qh, ql, kh, kl, vo,
                                           x, gamma, out, att);
}

// Round 12
// 312.405 us; speedup vs baseline: 1.1584x; 1.1028x over previous
//
#include <hip/hip_runtime.h>
#include <hip/hip_bf16.h>

// Problem constants: B=4, C=256, H=W=64, N=4096, Cq=32
#define NB 4
#define NC 256
#define NQ 32
#define NN 4096
#define LOG2E 1.4426950408889634f
#define SHIFT 44.0f   // fixed softmax shift: E>=0 (post-ReLU)
#define PSTR 80       // private P-tile LDS row stride (64 B data + 16 B pad)

typedef __attribute__((ext_vector_type(4))) float f32x4;
typedef __attribute__((ext_vector_type(8))) short s16x8;

#define MFMA16(a, b, c) __builtin_amdgcn_mfma_f32_16x16x32_bf16((a), (b), (c), 0, 0, 0)

// native 2^x (v_exp_f32); avoids math.h __exp2f macro clash
__device__ __forceinline__ float fexp2(float x) {
    float r;
    asm("v_exp_f32 %0, %1" : "=v"(r) : "v"(x));
    return r;
}
__device__ __forceinline__ float bf2f(unsigned short s) {
    return __uint_as_float(((unsigned int)s) << 16);
}
__device__ __forceinline__ unsigned long long packbf4(f32x4 p) {
    union { __hip_bfloat16 h[4]; unsigned long long u; } pk;
    #pragma unroll
    for (int j = 0; j < 4; ++j) pk.h[j] = __float2bfloat16(p[j]);
    return pk.u;
}

// ---------------- K1: fused QKV 1x1-conv projection (fp32 VALU) ----------------
// grid (N/32, B), block 512, LDS x tile [256c][32n] = 32 KB.
__global__ __launch_bounds__(512, 3) void k_proj(
    const float* __restrict__ x,
    const float* __restrict__ Wq, const float* __restrict__ bq,
    const float* __restrict__ Wk, const float* __restrict__ bk,
    const float* __restrict__ Wv, const float* __restrict__ bv,
    __hip_bfloat16* __restrict__ qh, __hip_bfloat16* __restrict__ ql,
    __hip_bfloat16* __restrict__ kh, __hip_bfloat16* __restrict__ kl,
    __hip_bfloat16* __restrict__ vo)
{
    __shared__ __align__(16) float xs[NC * 32];
    const int b  = blockIdx.y;
    const int n0 = blockIdx.x * 32;
    const int t  = threadIdx.x;

    {
        const float* xb = x + (size_t)b * NC * NN + n0;
        #pragma unroll
        for (int it = 0; it < 4; ++it) {
            int i4 = t + it * 512;            // 0..2047
            int c  = i4 >> 3;
            int nq = (i4 & 7) << 2;
            float4 v4 = *(const float4*)(xb + (size_t)c * NN + nq);
            *(float4*)&xs[c * 32 + nq] = v4;
        }
    }
    __syncthreads();

    const int g  = t >> 3;            // 0..63
    const int n4 = (t & 7) << 2;      // 0,4,...,28

    const float* Wr[5];
    float a[5][4];
    #pragma unroll
    for (int j = 0; j < 5; ++j) {
        int o = g + 64 * j;
        const float* Wrow; float bias;
        if (o < 32)      { Wrow = Wq + o * NC;        bias = bq[o]; }
        else if (o < 64) { Wrow = Wk + (o - 32) * NC; bias = bk[o - 32]; }
        else             { Wrow = Wv + (o - 64) * NC; bias = bv[o - 64]; }
        Wr[j] = Wrow;
        a[j][0] = a[j][1] = a[j][2] = a[j][3] = bias;
    }

    #pragma unroll 2
    for (int c0 = 0; c0 < NC; c0 += 4) {
        float4 xv[4];
        #pragma unroll
        for (int i = 0; i < 4; ++i) xv[i] = *(const float4*)&xs[(c0 + i) * 32 + n4];
        #pragma unroll
        for (int j = 0; j < 5; ++j) {
            float4 w = *(const float4*)(Wr[j] + c0);
            a[j][0] += w.x * xv[0].x + w.y * xv[1].x + w.z * xv[2].x + w.w * xv[3].x;
            a[j][1] += w.x * xv[0].y + w.y * xv[1].y + w.z * xv[2].y + w.w * xv[3].y;
            a[j][2] += w.x * xv[0].z + w.y * xv[1].z + w.z * xv[2].z + w.w * xv[3].z;
            a[j][3] += w.x * xv[0].w + w.y * xv[1].w + w.z * xv[2].w + w.w * xv[3].w;
        }
    }

    #pragma unroll
    for (int j = 0; j < 5; ++j) {
        int o = g + 64 * j;
        float a0 = fmaxf(a[j][0], 0.f), a1 = fmaxf(a[j][1], 0.f);
        float a2 = fmaxf(a[j][2], 0.f), a3 = fmaxf(a[j][3], 0.f);
        int nn = n0 + n4;
        if (o < 64) {
            __hip_bfloat16 *dh, *dl; int c; float sc;
            if (o < 32) { dh = qh; dl = ql; c = o;      sc = LOG2E; }  // exp2 domain
            else        { dh = kh; dl = kl; c = o - 32; sc = 1.0f;  }
            float vals[4] = {a0 * sc, a1 * sc, a2 * sc, a3 * sc};
            #pragma unroll
            for (int i = 0; i < 4; ++i) {
                float vv = vals[i];
                __hip_bfloat16 h = __float2bfloat16(vv);
                float lo = vv - __bfloat162float(h);
                size_t base = ((size_t)b * NN + nn + i) * NQ + c;
                dh[base] = h;
                dl[base] = __float2bfloat16(lo);
            }
        } else {
            union { __hip_bfloat16 h[4]; unsigned long long u; } pk;
            pk.h[0] = __float2bfloat16(a0); pk.h[1] = __float2bfloat16(a1);
            pk.h[2] = __float2bfloat16(a2); pk.h[3] = __float2bfloat16(a3);
            *(unsigned long long*)(vo + ((size_t)b * NC + (o - 64)) * NN + nn) = pk.u;
        }
    }
}

// ---------------- K2: fused attention — barrier-free, lane-contiguous writes ----------------
// grid 512 (XCD-swizzled), block 256 = 4 waves. Block = 32n x 256c; wave = 64c x 32n.
// Per 32-m step (per wave, fully independent):
//   QK: two identity 16x16 tiles per n-sub (6 MFMA) -> exp2 -> P (fp32).
//   P -> bf16 -> private LDS tile [32 rows][32 m] (stride 80 B, bank-spread).
//   PV frag: 2x ds_read_b128 (lane (r,hi) = P[r][hi*8..+7]) -> 8 PV MFMAs.
//   att: 4x { ds_read_b64 lane-contiguous (lane L -> row L>>3, cols (L&7)*4)
//             -> bf16->fp32 -> NT f32x4; 8 adjacent lanes = 128 B contiguous }.
//   k,v prefetched one step ahead. NO barriers in the loop.
__global__ __launch_bounds__(256, 2) void k_fused(
    const __hip_bfloat16* __restrict__ qh, const __hip_bfloat16* __restrict__ ql,
    const __hip_bfloat16* __restrict__ kh, const __hip_bfloat16* __restrict__ kl,
    const __hip_bfloat16* __restrict__ v,
    const float* __restrict__ x, const float* __restrict__ gamma,
    float* __restrict__ out, float* __restrict__ att)
{
    __shared__ __align__(16) char plds[4 * 32 * PSTR];   // 10 KB: 4 waves x [32 r][80 B]
    __shared__ float redS[4][16];
    __shared__ float finI[32];

    // XCD chunked swizzle: 64 consecutive flat blocks per XCD (half a batch)
    const int bid  = blockIdx.x;
    const int flat = (bid & 7) * 64 + (bid >> 3);
    const int b    = flat >> 7;
    const int n0   = (flat & 127) * 32;

    const int t = threadIdx.x, wv = t >> 6, lane = t & 63;
    const int r = lane & 15, hi = lane >> 4, kc = hi * 8;

    const __hip_bfloat16* khb = kh + (size_t)b * NN * NQ;
    const __hip_bfloat16* klb = kl + (size_t)b * NN * NQ;
    const __hip_bfloat16* vb  = v  + (size_t)b * NC * NN;
    const __hip_bfloat16* qhb = qh + ((size_t)b * NN + n0) * NQ;
    const __hip_bfloat16* qlb = ql + ((size_t)b * NN + n0) * NQ;

    // ---- pass 1: fixed-shift row sums (rs = wv&1 row-half, mh = wv>>1 m-half) ----
    {
        const int rs = wv & 1, mh = wv >> 1;
        const s16x8 aqh = *(const s16x8*)(qhb + (size_t)(rs * 16 + r) * NQ + kc);
        const s16x8 aql = *(const s16x8*)(qlb + (size_t)(rs * 16 + r) * NQ + kc);
        const int mb = mh * 2048;
        float S = 0.f;
        s16x8 c0h = *(const s16x8*)(khb + (size_t)(mb + r) * NQ + kc);
        s16x8 c0l = *(const s16x8*)(klb + (size_t)(mb + r) * NQ + kc);
        s16x8 c1h = *(const s16x8*)(khb + (size_t)(mb + 16 + r) * NQ + kc);
        s16x8 c1l = *(const s16x8*)(klb + (size_t)(mb + 16 + r) * NQ + kc);
        #pragma unroll 1
        for (int it = 0; it < 64; ++it) {
            s16x8 u0h = c0h, u0l = c0l, u1h = c1h, u1l = c1l;
            if (it < 63) {
                int m = mb + (it + 1) * 32;
                c0h = *(const s16x8*)(khb + (size_t)(m + r) * NQ + kc);
                c0l = *(const s16x8*)(klb + (size_t)(m + r) * NQ + kc);
                c1h = *(const s16x8*)(khb + (size_t)(m + 16 + r) * NQ + kc);
                c1l = *(const s16x8*)(klb + (size_t)(m + 16 + r) * NQ + kc);
            }
            f32x4 e0 = {0.f, 0.f, 0.f, 0.f}, e1 = {0.f, 0.f, 0.f, 0.f};
            e0 = MFMA16(u0h, aqh, e0); e0 = MFMA16(u0l, aqh, e0); e0 = MFMA16(u0h, aql, e0);
            e1 = MFMA16(u1h, aqh, e1); e1 = MFMA16(u1l, aqh, e1); e1 = MFMA16(u1h, aql, e1);
            S += fexp2(e0[0] - SHIFT) + fexp2(e0[1] - SHIFT) +
                 fexp2(e0[2] - SHIFT) + fexp2(e0[3] - SHIFT) +
                 fexp2(e1[0] - SHIFT) + fexp2(e1[1] - SHIFT) +
                 fexp2(e1[2] - SHIFT) + fexp2(e1[3] - SHIFT);
        }
        S += __shfl_xor(S, 16);
        S += __shfl_xor(S, 32);
        if (lane < 16) redS[wv][r] = S;
    }
    __syncthreads();
    if (t < 32) {
        const int rs = t >> 4, tl = t & 15;
        finI[t] = 1.0f / (redS[rs][tl] + redS[2 + rs][tl]);
    }
    __syncthreads();

    // ---- pass 2: barrier-free fused sweep ----
    const int cw = wv * 64;
    const s16x8 aqh0 = *(const s16x8*)(qhb + (size_t)(r) * NQ + kc);
    const s16x8 aql0 = *(const s16x8*)(qlb + (size_t)(r) * NQ + kc);
    const s16x8 aqh1 = *(const s16x8*)(qhb + (size_t)(16 + r) * NQ + kc);
    const s16x8 aql1 = *(const s16x8*)(qlb + (size_t)(16 + r) * NQ + kc);
    const float fI0 = finI[r], fI1 = finI[16 + r];

    // k row pointers (identity tiles: tile0 row = r, tile1 row = 16 + r)
    const __hip_bfloat16* kh0 = khb + (size_t)r * NQ + kc;
    const __hip_bfloat16* kl0 = klb + (size_t)r * NQ + kc;
    const __hip_bfloat16* kh1 = khb + (size_t)(16 + r) * NQ + kc;
    const __hip_bfloat16* kl1 = klb + (size_t)(16 + r) * NQ + kc;
    const __hip_bfloat16* vr0 = vb + (size_t)(cw + r) * NN + kc;
    const __hip_bfloat16* vr1 = vb + (size_t)(cw + 16 + r) * NN + kc;
    const __hip_bfloat16* vr2 = vb + (size_t)(cw + 32 + r) * NN + kc;
    const __hip_bfloat16* vr3 = vb + (size_t)(cw + 48 + r) * NN + kc;

    // private P-tile addresses (stride-80 rows; rows 0-15 = ns0, 16-31 = ns1)
    char* ptile = plds + wv * (32 * PSTR);
    const int w00 = r * PSTR + hi * 8;            // p00: row r,    cols hi*4..+3... (8 B)
    const int w01 = r * PSTR + 32 + hi * 8;       // p01: row r,    cols 16+hi*4
    const int w10 = (16 + r) * PSTR + hi * 8;     // p10: row 16+r
    const int w11 = (16 + r) * PSTR + 32 + hi * 8;
    const int rd0 = r * PSTR + hi * 16;           // PV frag: row r,    cols hi*8..+7
    const int rd1 = (16 + r) * PSTR + hi * 16;    //          row 16+r
    // att readback: lane L -> row L>>3 (+8i), cols (L&7)*4..+3
    const int l8 = lane & 7, lr = lane >> 3;
    const int rda = lr * PSTR + l8 * 8;
    float* awr = att + ((size_t)b * NN + n0 + lr) * NN + l8 * 4;

    f32x4 acc[4][2] = {};
    s16x8 kA[4], kB[4], vA[4], vB[4];

    // prologue: step-0 fragments
    kA[0] = *(const s16x8*)(kh0); kA[1] = *(const s16x8*)(kl0);
    kA[2] = *(const s16x8*)(kh1); kA[3] = *(const s16x8*)(kl1);
    vA[0] = *(const s16x8*)(vr0); vA[1] = *(const s16x8*)(vr1);
    vA[2] = *(const s16x8*)(vr2); vA[3] = *(const s16x8*)(vr3);

    auto sub = [&](int s, s16x8 (&kC)[4], s16x8 (&kN)[4],
                   s16x8 (&vC)[4], s16x8 (&vN)[4]) {
        const int m0 = s * 32;
        if (s < 127) {
            const size_t mo = (size_t)(m0 + 32) * NQ;
            kN[0] = *(const s16x8*)(kh0 + mo); kN[1] = *(const s16x8*)(kl0 + mo);
            kN[2] = *(const s16x8*)(kh1 + mo); kN[3] = *(const s16x8*)(kl1 + mo);
            vN[0] = *(const s16x8*)(vr0 + m0 + 32); vN[1] = *(const s16x8*)(vr1 + m0 + 32);
            vN[2] = *(const s16x8*)(vr2 + m0 + 32); vN[3] = *(const s16x8*)(vr3 + m0 + 32);
        }
        // QK identity tiles: lane (r,hi) j-th of tile T = E[m0 + 16T + hi*4 + j][n=ns*16+r]
        f32x4 e00 = {0.f,0.f,0.f,0.f}, e01 = {0.f,0.f,0.f,0.f};
        f32x4 e10 = {0.f,0.f,0.f,0.f}, e11 = {0.f,0.f,0.f,0.f};
        e00 = MFMA16(kC[0], aqh0, e00); e00 = MFMA16(kC[1], aqh0, e00); e00 = MFMA16(kC[0], aql0, e00);
        e01 = MFMA16(kC[2], aqh0, e01); e01 = MFMA16(kC[3], aqh0, e01); e01 = MFMA16(kC[2], aql0, e01);
        e10 = MFMA16(kC[0], aqh1, e10); e10 = MFMA16(kC[1], aqh1, e10); e10 = MFMA16(kC[0], aql1, e10);
        e11 = MFMA16(kC[2], aqh1, e11); e11 = MFMA16(kC[3], aqh1, e11); e11 = MFMA16(kC[2], aql1, e11);

        f32x4 p00, p01, p10, p11;
        #pragma unroll
        for (int j = 0; j < 4; ++j) {
            p00[j] = fexp2(e00[j] - SHIFT) * fI0;
            p01[j] = fexp2(e01[j] - SHIFT) * fI0;
            p10[j] = fexp2(e10[j] - SHIFT) * fI1;
            p11[j] = fexp2(e11[j] - SHIFT) * fI1;
        }
        // P -> bf16 -> private LDS tile
        *(unsigned long long*)(ptile + w00) = packbf4(p00);
        *(unsigned long long*)(ptile + w01) = packbf4(p01);
        *(unsigned long long*)(ptile + w10) = packbf4(p10);
        *(unsigned long long*)(ptile + w11) = packbf4(p11);

        // PV fragments (lane (r,hi) = P[row][hi*8..+7])
        s16x8 pf0 = *(const s16x8*)(ptile + rd0);
        s16x8 pf1 = *(const s16x8*)(ptile + rd1);

        // att: lane-contiguous readback + NT store (8 lanes = 128 B contiguous/row)
        #pragma unroll
        for (int i = 0; i < 4; ++i) {
            unsigned long long pv =
                *(const unsigned long long*)(ptile + i * 8 * PSTR + rda);
            f32x4 w;
            w[0] = bf2f((unsigned short)(pv));
            w[1] = bf2f((unsigned short)(pv >> 16));
            w[2] = bf2f((unsigned short)(pv >> 32));
            w[3] = bf2f((unsigned short)(pv >> 48));
            __builtin_nontemporal_store(w, (f32x4*)(awr + (size_t)i * 8 * NN + m0));
        }

        // PV: 4 c-subtiles x 2 n-subtiles
        acc[0][0] = MFMA16(vC[0], pf0, acc[0][0]);
        acc[1][0] = MFMA16(vC[1], pf0, acc[1][0]);
        acc[2][0] = MFMA16(vC[2], pf0, acc[2][0]);
        acc[3][0] = MFMA16(vC[3], pf0, acc[3][0]);
        acc[0][1] = MFMA16(vC[0], pf1, acc[0][1]);
        acc[1][1] = MFMA16(vC[1], pf1, acc[1][1]);
        acc[2][1] = MFMA16(vC[2], pf1, acc[2][1]);
        acc[3][1] = MFMA16(vC[3], pf1, acc[3][1]);
    };

    #pragma unroll 1
    for (int it = 0; it < 64; ++it) {
        sub(2 * it,     kA, kB, vA, vB);
        sub(2 * it + 1, kB, kA, vB, vA);
    }

    // epilogue: out = gamma*acc + x  (c = cw + cc*16 + hi*4 + j, n = n0 + ns*16 + r)
    const float gm = gamma[0];
    #pragma unroll
    for (int cc = 0; cc < 4; ++cc) {
        #pragma unroll
        for (int ns = 0; ns < 2; ++ns) {
            #pragma unroll
            for (int j = 0; j < 4; ++j) {
                int c = cw + cc * 16 + hi * 4 + j;
                size_t idx = ((size_t)b * NC + c) * NN + n0 + ns * 16 + r;
                out[idx] = gm * acc[cc][ns][j] + x[idx];
            }
        }
    }
}

extern "C" void kernel_launch(void* const* d_in, const int* in_sizes, int n_in,
                              void* d_out, int out_size, void* d_ws, size_t ws_size,
                              hipStream_t stream) {
    const float* x     = (const float*)d_in[0];
    const float* Wq    = (const float*)d_in[1];
    const float* bq    = (const float*)d_in[2];
    const float* Wk    = (const float*)d_in[3];
    const float* bk    = (const float*)d_in[4];
    const float* Wv    = (const float*)d_in[5];
    const float* bv    = (const float*)d_in[6];
    const float* gamma = (const float*)d_in[7];

    float* out = (float*)d_out;
    float* att = out + (size_t)NB * NC * NN;   // attention output region (268 MB)

    // workspace: qh | ql | kh | kl (each B*N*32 bf16 = 1 MB) | v bf16 (8 MB)
    const size_t qk_elems = (size_t)NB * NN * NQ;
    __hip_bfloat16* qh = (__hip_bfloat16*)d_ws;
    __hip_bfloat16* ql = qh + qk_elems;
    __hip_bfloat16* kh = ql + qk_elems;
    __hip_bfloat16* kl = kh + qk_elems;
    __hip_bfloat16* vo = kl + qk_elems;

    k_proj <<<dim3(NN / 32, NB), 512, 0, stream>>>(x, Wq, bq, Wk, bk, Wv, bv,
                                                   qh, ql, kh, kl, vo);
    k_fused<<<dim3(512), 256, 0, stream>>>(qh, ql, kh, kl, vo,
                                           x, gamma, out, att);
}

// Round 13
// 262.042 us; speedup vs baseline: 1.3810x; 1.1922x over previous
//
#include <hip/hip_runtime.h>
#include <hip/hip_bf16.h>

// Problem constants: B=4, C=256, H=W=64, N=4096, Cq=32
#define NB 4
#define NC 256
#define NQ 32
#define NN 4096
#define LOG2E 1.4426950408889634f
#define SHIFT 44.0f   // fixed softmax shift: E>=0 (post-ReLU)
#define PSTR 80       // private P-tile LDS row stride (64 B data + 16 B pad)

typedef __attribute__((ext_vector_type(4))) float f32x4;
typedef __attribute__((ext_vector_type(8))) short s16x8;

#define MFMA16(a, b, c) __builtin_amdgcn_mfma_f32_16x16x32_bf16((a), (b), (c), 0, 0, 0)

// native 2^x (v_exp_f32); avoids math.h __exp2f macro clash
__device__ __forceinline__ float fexp2(float x) {
    float r;
    asm("v_exp_f32 %0, %1" : "=v"(r) : "v"(x));
    return r;
}
__device__ __forceinline__ float bf2f(unsigned short s) {
    return __uint_as_float(((unsigned int)s) << 16);
}
__device__ __forceinline__ unsigned long long packbf4(f32x4 p) {
    union { __hip_bfloat16 h[4]; unsigned long long u; } pk;
    #pragma unroll
    for (int j = 0; j < 4; ++j) pk.h[j] = __float2bfloat16(p[j]);
    return pk.u;
}

// ---------------- K1: fused QKV 1x1-conv projection (fp32 VALU) ----------------
// grid (N/32, B), block 512, LDS x tile [256c][32n] = 32 KB.
__global__ __launch_bounds__(512, 3) void k_proj(
    const float* __restrict__ x,
    const float* __restrict__ Wq, const float* __restrict__ bq,
    const float* __restrict__ Wk, const float* __restrict__ bk,
    const float* __restrict__ Wv, const float* __restrict__ bv,
    __hip_bfloat16* __restrict__ qh, __hip_bfloat16* __restrict__ ql,
    __hip_bfloat16* __restrict__ kh, __hip_bfloat16* __restrict__ kl,
    __hip_bfloat16* __restrict__ vo)
{
    __shared__ __align__(16) float xs[NC * 32];
    const int b  = blockIdx.y;
    const int n0 = blockIdx.x * 32;
    const int t  = threadIdx.x;

    {
        const float* xb = x + (size_t)b * NC * NN + n0;
        #pragma unroll
        for (int it = 0; it < 4; ++it) {
            int i4 = t + it * 512;            // 0..2047
            int c  = i4 >> 3;
            int nq = (i4 & 7) << 2;
            float4 v4 = *(const float4*)(xb + (size_t)c * NN + nq);
            *(float4*)&xs[c * 32 + nq] = v4;
        }
    }
    __syncthreads();

    const int g  = t >> 3;            // 0..63
    const int n4 = (t & 7) << 2;      // 0,4,...,28

    const float* Wr[5];
    float a[5][4];
    #pragma unroll
    for (int j = 0; j < 5; ++j) {
        int o = g + 64 * j;
        const float* Wrow; float bias;
        if (o < 32)      { Wrow = Wq + o * NC;        bias = bq[o]; }
        else if (o < 64) { Wrow = Wk + (o - 32) * NC; bias = bk[o - 32]; }
        else             { Wrow = Wv + (o - 64) * NC; bias = bv[o - 64]; }
        Wr[j] = Wrow;
        a[j][0] = a[j][1] = a[j][2] = a[j][3] = bias;
    }

    #pragma unroll 2
    for (int c0 = 0; c0 < NC; c0 += 4) {
        float4 xv[4];
        #pragma unroll
        for (int i = 0; i < 4; ++i) xv[i] = *(const float4*)&xs[(c0 + i) * 32 + n4];
        #pragma unroll
        for (int j = 0; j < 5; ++j) {
            float4 w = *(const float4*)(Wr[j] + c0);
            a[j][0] += w.x * xv[0].x + w.y * xv[1].x + w.z * xv[2].x + w.w * xv[3].x;
            a[j][1] += w.x * xv[0].y + w.y * xv[1].y + w.z * xv[2].y + w.w * xv[3].y;
            a[j][2] += w.x * xv[0].z + w.y * xv[1].z + w.z * xv[2].z + w.w * xv[3].z;
            a[j][3] += w.x * xv[0].w + w.y * xv[1].w + w.z * xv[2].w + w.w * xv[3].w;
        }
    }

    #pragma unroll
    for (int j = 0; j < 5; ++j) {
        int o = g + 64 * j;
        float a0 = fmaxf(a[j][0], 0.f), a1 = fmaxf(a[j][1], 0.f);
        float a2 = fmaxf(a[j][2], 0.f), a3 = fmaxf(a[j][3], 0.f);
        int nn = n0 + n4;
        if (o < 64) {
            __hip_bfloat16 *dh, *dl; int c; float sc;
            if (o < 32) { dh = qh; dl = ql; c = o;      sc = LOG2E; }  // exp2 domain
            else        { dh = kh; dl = kl; c = o - 32; sc = 1.0f;  }
            float vals[4] = {a0 * sc, a1 * sc, a2 * sc, a3 * sc};
            #pragma unroll
            for (int i = 0; i < 4; ++i) {
                float vv = vals[i];
                __hip_bfloat16 h = __float2bfloat16(vv);
                float lo = vv - __bfloat162float(h);
                size_t base = ((size_t)b * NN + nn + i) * NQ + c;
                dh[base] = h;
                dl[base] = __float2bfloat16(lo);
            }
        } else {
            union { __hip_bfloat16 h[4]; unsigned long long u; } pk;
            pk.h[0] = __float2bfloat16(a0); pk.h[1] = __float2bfloat16(a1);
            pk.h[2] = __float2bfloat16(a2); pk.h[3] = __float2bfloat16(a3);
            *(unsigned long long*)(vo + ((size_t)b * NC + (o - 64)) * NN + nn) = pk.u;
        }
    }
}

// ---------------- K2: fused attention — barrier-free, DEDUPED att writes ----------------
// grid 512 (XCD-swizzled), block 256 = 4 waves. Block = 32n x 256c; wave = 64c x 32n.
// All 4 waves compute the same 32n P tile (each needs it for its own c-slice PV),
// but att is stored by exactly ONE wave per row-group: wave wv stores rows
// n0 + wv*8 + (lane>>3), cols (lane&7)*4.. -> 8 rows x 128 B lane-contiguous per
// step per wave, each att row written once per block (R12 wrote each row 4x!).
// NO barriers in the loop; k,v prefetched one step ahead.
__global__ __launch_bounds__(256, 2) void k_fused(
    const __hip_bfloat16* __restrict__ qh, const __hip_bfloat16* __restrict__ ql,
    const __hip_bfloat16* __restrict__ kh, const __hip_bfloat16* __restrict__ kl,
    const __hip_bfloat16* __restrict__ v,
    const float* __restrict__ x, const float* __restrict__ gamma,
    float* __restrict__ out, float* __restrict__ att)
{
    __shared__ __align__(16) char plds[4 * 32 * PSTR];   // 10 KB: 4 waves x [32 r][80 B]
    __shared__ float redS[4][16];
    __shared__ float finI[32];

    // XCD chunked swizzle: 64 consecutive flat blocks per XCD (half a batch)
    const int bid  = blockIdx.x;
    const int flat = (bid & 7) * 64 + (bid >> 3);
    const int b    = flat >> 7;
    const int n0   = (flat & 127) * 32;

    const int t = threadIdx.x, wv = t >> 6, lane = t & 63;
    const int r = lane & 15, hi = lane >> 4, kc = hi * 8;

    const __hip_bfloat16* khb = kh + (size_t)b * NN * NQ;
    const __hip_bfloat16* klb = kl + (size_t)b * NN * NQ;
    const __hip_bfloat16* vb  = v  + (size_t)b * NC * NN;
    const __hip_bfloat16* qhb = qh + ((size_t)b * NN + n0) * NQ;
    const __hip_bfloat16* qlb = ql + ((size_t)b * NN + n0) * NQ;

    // ---- pass 1: fixed-shift row sums (rs = wv&1 row-half, mh = wv>>1 m-half) ----
    {
        const int rs = wv & 1, mh = wv >> 1;
        const s16x8 aqh = *(const s16x8*)(qhb + (size_t)(rs * 16 + r) * NQ + kc);
        const s16x8 aql = *(const s16x8*)(qlb + (size_t)(rs * 16 + r) * NQ + kc);
        const int mb = mh * 2048;
        float S = 0.f;
        s16x8 c0h = *(const s16x8*)(khb + (size_t)(mb + r) * NQ + kc);
        s16x8 c0l = *(const s16x8*)(klb + (size_t)(mb + r) * NQ + kc);
        s16x8 c1h = *(const s16x8*)(khb + (size_t)(mb + 16 + r) * NQ + kc);
        s16x8 c1l = *(const s16x8*)(klb + (size_t)(mb + 16 + r) * NQ + kc);
        #pragma unroll 1
        for (int it = 0; it < 64; ++it) {
            s16x8 u0h = c0h, u0l = c0l, u1h = c1h, u1l = c1l;
            if (it < 63) {
                int m = mb + (it + 1) * 32;
                c0h = *(const s16x8*)(khb + (size_t)(m + r) * NQ + kc);
                c0l = *(const s16x8*)(klb + (size_t)(m + r) * NQ + kc);
                c1h = *(const s16x8*)(khb + (size_t)(m + 16 + r) * NQ + kc);
                c1l = *(const s16x8*)(klb + (size_t)(m + 16 + r) * NQ + kc);
            }
            f32x4 e0 = {0.f, 0.f, 0.f, 0.f}, e1 = {0.f, 0.f, 0.f, 0.f};
            e0 = MFMA16(u0h, aqh, e0); e0 = MFMA16(u0l, aqh, e0); e0 = MFMA16(u0h, aql, e0);
            e1 = MFMA16(u1h, aqh, e1); e1 = MFMA16(u1l, aqh, e1); e1 = MFMA16(u1h, aql, e1);
            S += fexp2(e0[0] - SHIFT) + fexp2(e0[1] - SHIFT) +
                 fexp2(e0[2] - SHIFT) + fexp2(e0[3] - SHIFT) +
                 fexp2(e1[0] - SHIFT) + fexp2(e1[1] - SHIFT) +
                 fexp2(e1[2] - SHIFT) + fexp2(e1[3] - SHIFT);
        }
        S += __shfl_xor(S, 16);
        S += __shfl_xor(S, 32);
        if (lane < 16) redS[wv][r] = S;
    }
    __syncthreads();
    if (t < 32) {
        const int rs = t >> 4, tl = t & 15;
        finI[t] = 1.0f / (redS[rs][tl] + redS[2 + rs][tl]);
    }
    __syncthreads();

    // ---- pass 2: barrier-free fused sweep ----
    const int cw = wv * 64;
    const s16x8 aqh0 = *(const s16x8*)(qhb + (size_t)(r) * NQ + kc);
    const s16x8 aql0 = *(const s16x8*)(qlb + (size_t)(r) * NQ + kc);
    const s16x8 aqh1 = *(const s16x8*)(qhb + (size_t)(16 + r) * NQ + kc);
    const s16x8 aql1 = *(const s16x8*)(qlb + (size_t)(16 + r) * NQ + kc);
    const float fI0 = finI[r], fI1 = finI[16 + r];

    // k row pointers (identity tiles: tile0 row = r, tile1 row = 16 + r)
    const __hip_bfloat16* kh0 = khb + (size_t)r * NQ + kc;
    const __hip_bfloat16* kl0 = klb + (size_t)r * NQ + kc;
    const __hip_bfloat16* kh1 = khb + (size_t)(16 + r) * NQ + kc;
    const __hip_bfloat16* kl1 = klb + (size_t)(16 + r) * NQ + kc;
    const __hip_bfloat16* vr0 = vb + (size_t)(cw + r) * NN + kc;
    const __hip_bfloat16* vr1 = vb + (size_t)(cw + 16 + r) * NN + kc;
    const __hip_bfloat16* vr2 = vb + (size_t)(cw + 32 + r) * NN + kc;
    const __hip_bfloat16* vr3 = vb + (size_t)(cw + 48 + r) * NN + kc;

    // private P-tile addresses (stride-80 rows; rows 0-15 = ns0, 16-31 = ns1)
    char* ptile = plds + wv * (32 * PSTR);
    const int w00 = r * PSTR + hi * 8;            // p00: row r,    cols hi*4..  (8 B)
    const int w01 = r * PSTR + 32 + hi * 8;       // p01: row r,    cols 16+hi*4
    const int w10 = (16 + r) * PSTR + hi * 8;     // p10: row 16+r
    const int w11 = (16 + r) * PSTR + 32 + hi * 8;
    const int rd0 = r * PSTR + hi * 16;           // PV frag: row r,    cols hi*8..+7
    const int rd1 = (16 + r) * PSTR + hi * 16;    //          row 16+r
    // att store (DEDUPED): wave wv owns rows n0 + wv*8 + (lane>>3)
    const int l8 = lane & 7, lr = lane >> 3;
    const int rda = (wv * 8 + lr) * PSTR + l8 * 8;
    float* awr = att + ((size_t)b * NN + n0 + wv * 8 + lr) * NN + l8 * 4;

    f32x4 acc[4][2] = {};
    s16x8 kA[4], kB[4], vA[4], vB[4];

    // prologue: step-0 fragments
    kA[0] = *(const s16x8*)(kh0); kA[1] = *(const s16x8*)(kl0);
    kA[2] = *(const s16x8*)(kh1); kA[3] = *(const s16x8*)(kl1);
    vA[0] = *(const s16x8*)(vr0); vA[1] = *(const s16x8*)(vr1);
    vA[2] = *(const s16x8*)(vr2); vA[3] = *(const s16x8*)(vr3);

    auto sub = [&](int s, s16x8 (&kC)[4], s16x8 (&kN)[4],
                   s16x8 (&vC)[4], s16x8 (&vN)[4]) {
        const int m0 = s * 32;
        if (s < 127) {
            const size_t mo = (size_t)(m0 + 32) * NQ;
            kN[0] = *(const s16x8*)(kh0 + mo); kN[1] = *(const s16x8*)(kl0 + mo);
            kN[2] = *(const s16x8*)(kh1 + mo); kN[3] = *(const s16x8*)(kl1 + mo);
            vN[0] = *(const s16x8*)(vr0 + m0 + 32); vN[1] = *(const s16x8*)(vr1 + m0 + 32);
            vN[2] = *(const s16x8*)(vr2 + m0 + 32); vN[3] = *(const s16x8*)(vr3 + m0 + 32);
        }
        // QK identity tiles: lane (r,hi) j-th of tile T = E[m0 + 16T + hi*4 + j][n=ns*16+r]
        f32x4 e00 = {0.f,0.f,0.f,0.f}, e01 = {0.f,0.f,0.f,0.f};
        f32x4 e10 = {0.f,0.f,0.f,0.f}, e11 = {0.f,0.f,0.f,0.f};
        e00 = MFMA16(kC[0], aqh0, e00); e00 = MFMA16(kC[1], aqh0, e00); e00 = MFMA16(kC[0], aql0, e00);
        e01 = MFMA16(kC[2], aqh0, e01); e01 = MFMA16(kC[3], aqh0, e01); e01 = MFMA16(kC[2], aql0, e01);
        e10 = MFMA16(kC[0], aqh1, e10); e10 = MFMA16(kC[1], aqh1, e10); e10 = MFMA16(kC[0], aql1, e10);
        e11 = MFMA16(kC[2], aqh1, e11); e11 = MFMA16(kC[3], aqh1, e11); e11 = MFMA16(kC[2], aql1, e11);

        f32x4 p00, p01, p10, p11;
        #pragma unroll
        for (int j = 0; j < 4; ++j) {
            p00[j] = fexp2(e00[j] - SHIFT) * fI0;
            p01[j] = fexp2(e01[j] - SHIFT) * fI0;
            p10[j] = fexp2(e10[j] - SHIFT) * fI1;
            p11[j] = fexp2(e11[j] - SHIFT) * fI1;
        }
        // P -> bf16 -> private LDS tile
        *(unsigned long long*)(ptile + w00) = packbf4(p00);
        *(unsigned long long*)(ptile + w01) = packbf4(p01);
        *(unsigned long long*)(ptile + w10) = packbf4(p10);
        *(unsigned long long*)(ptile + w11) = packbf4(p11);

        // PV fragments (lane (r,hi) = P[row][hi*8..+7])
        s16x8 pf0 = *(const s16x8*)(ptile + rd0);
        s16x8 pf1 = *(const s16x8*)(ptile + rd1);

        // att: DEDUPED — this wave stores only its 8-row group (128 B/row,
        // lane-contiguous: 8 adjacent lanes cover one row segment)
        {
            unsigned long long pv = *(const unsigned long long*)(ptile + rda);
            f32x4 w;
            w[0] = bf2f((unsigned short)(pv));
            w[1] = bf2f((unsigned short)(pv >> 16));
            w[2] = bf2f((unsigned short)(pv >> 32));
            w[3] = bf2f((unsigned short)(pv >> 48));
            __builtin_nontemporal_store(w, (f32x4*)(awr + m0));
        }

        // PV: 4 c-subtiles x 2 n-subtiles
        acc[0][0] = MFMA16(vC[0], pf0, acc[0][0]);
        acc[1][0] = MFMA16(vC[1], pf0, acc[1][0]);
        acc[2][0] = MFMA16(vC[2], pf0, acc[2][0]);
        acc[3][0] = MFMA16(vC[3], pf0, acc[3][0]);
        acc[0][1] = MFMA16(vC[0], pf1, acc[0][1]);
        acc[1][1] = MFMA16(vC[1], pf1, acc[1][1]);
        acc[2][1] = MFMA16(vC[2], pf1, acc[2][1]);
        acc[3][1] = MFMA16(vC[3], pf1, acc[3][1]);
    };

    #pragma unroll 1
    for (int it = 0; it < 64; ++it) {
        sub(2 * it,     kA, kB, vA, vB);
        sub(2 * it + 1, kB, kA, vB, vA);
    }

    // epilogue: out = gamma*acc + x  (c = cw + cc*16 + hi*4 + j, n = n0 + ns*16 + r)
    const float gm = gamma[0];
    #pragma unroll
    for (int cc = 0; cc < 4; ++cc) {
        #pragma unroll
        for (int ns = 0; ns < 2; ++ns) {
            #pragma unroll
            for (int j = 0; j < 4; ++j) {
                int c = cw + cc * 16 + hi * 4 + j;
                size_t idx = ((size_t)b * NC + c) * NN + n0 + ns * 16 + r;
                out[idx] = gm * acc[cc][ns][j] + x[idx];
            }
        }
    }
}

extern "C" void kernel_launch(void* const* d_in, const int* in_sizes, int n_in,
                              void* d_out, int out_size, void* d_ws, size_t ws_size,
                              hipStream_t stream) {
    const float* x     = (const float*)d_in[0];
    const float* Wq    = (const float*)d_in[1];
    const float* bq    = (const float*)d_in[2];
    const float* Wk    = (const float*)d_in[3];
    const float* bk    = (const float*)d_in[4];
    const float* Wv    = (const float*)d_in[5];
    const float* bv    = (const float*)d_in[6];
    const float* gamma = (const float*)d_in[7];

    float* out = (float*)d_out;
    float* att = out + (size_t)NB * NC * NN;   // attention output region (268 MB)

    // workspace: qh | ql | kh | kl (each B*N*32 bf16 = 1 MB) | v bf16 (8 MB)
    const size_t qk_elems = (size_t)NB * NN * NQ;
    __hip_bfloat16* qh = (__hip_bfloat16*)d_ws;
    __hip_bfloat16* ql = qh + qk_elems;
    __hip_bfloat16* kh = ql + qk_elems;
    __hip_bfloat16* kl = kh + qk_elems;
    __hip_bfloat16* vo = kl + qk_elems;

    k_proj <<<dim3(NN / 32, NB), 512, 0, stream>>>(x, Wq, bq, Wk, bk, Wv, bv,
                                                   qh, ql, kh, kl, vo);
    k_fused<<<dim3(512), 256, 0, stream>>>(qh, ql, kh, kl, vo,
                                           x, gamma, out, att);
}